// Round 9
// baseline (240.598 us; speedup 1.0000x reference)
//
#include <hip/hip_runtime.h>
#include <hip/hip_bf16.h>
#include <math.h>

#define NN 200000
#define EE 100000
#define RAWD 172
#define MEMD 100
#define NKT 19            // k-tiles of 32 (K=608: 472 ih + 8 pad + 100 hh + 28 pad)
#define NCT 19            // col-tiles of 16, contiguous cols 0..303 (300 valid)
#define BM 64             // nodes per block
#define NTHR 512          // 8 waves
#define RS 616            // winner X row stride (shorts), 16B-aligned rows
#define RSL 136           // loser X row stride (shorts)
#define PLNA 308          // main plane row stride (floats)
#define PLNG 104          // gh plane row stride (floats)
#define NBLK 3125         // max blocks (NN/BM)

typedef __attribute__((ext_vector_type(8))) short bf16x8;
typedef __attribute__((ext_vector_type(4))) float f32x4;

__device__ inline unsigned short f2bf(float v) {
    __hip_bfloat16 h = __float2bfloat16(v);
    unsigned short u; __builtin_memcpy(&u, &h, 2); return u;
}

__device__ inline ushort4 pack4(float4 v) {
    ushort4 r;
    r.x = f2bf(v.x); r.y = f2bf(v.y); r.z = f2bf(v.z); r.w = f2bf(v.w);
    return r;
}

__device__ inline float fsigmoid(float x) { return 1.f / (1.f + __expf(-x)); }
__device__ inline float ftanh(float x) { return 1.f - 2.f / (__expf(2.f * x) + 1.f); }

// Branchless cos: f64 range reduction, f32 polys, quadrant select via bit tricks.
__device__ inline float fast_cos(float x) {
    double xd = (double)x;
    double kd = rint(xd * 0.6366197723675814);      // x * 2/pi
    double r_d = fma(kd, -1.5707963267948966, xd);  // x - k*pi/2
    float r = (float)r_d;
    int ki = (int)kd;
    float s = r * r;
    float c = fmaf(s, fmaf(s, fmaf(s, fmaf(s, 2.4801587e-5f, -1.3888889e-3f),
                                   4.1666668e-2f), -0.5f), 1.0f);
    float sn = r * fmaf(s, fmaf(s, fmaf(s, -1.9841270e-4f, 8.3333338e-3f),
                                -1.6666667e-1f), 1.0f);
    float base = (ki & 1) ? sn : c;
    return ((ki + 1) & 2) ? -base : base;
}

// ---- kernel 1: per-node winner via packed atomicMax key = (t<<32)|(eid+1) ----
__global__ void k_winner(const int* __restrict__ src, const int* __restrict__ dst,
                         const int* __restrict__ t, unsigned long long* __restrict__ keys) {
    int e = blockIdx.x * blockDim.x + threadIdx.x;
    if (e >= 2 * EE) return;
    int re = (e < EE) ? e : e - EE;
    int node = (e < EE) ? src[re] : dst[re];
    unsigned long long key =
        ((unsigned long long)(unsigned)t[re] << 32) | (unsigned)(e + 1);
    atomicMax(&keys[node], key);
}

// ---- kernel 2: decode winner; emit new_last_update; compact winner/loser lists ----
__global__ void k_nodeinfo(const unsigned long long* __restrict__ keys,
                           const int* __restrict__ src, const int* __restrict__ dst,
                           const int* __restrict__ lu,
                           int* __restrict__ other, int* __restrict__ ew,
                           float* __restrict__ dtv, float* __restrict__ out_lu,
                           int* __restrict__ list, int* __restrict__ cnt) {
    int n = blockIdx.x * blockDim.x + threadIdx.x;
    if (n >= NN) return;
    unsigned long long k = keys[n];
    if (k != 0ull) {
        int w = (int)(k & 0xffffffffull) - 1;
        int re = (w < EE) ? w : w - EE;
        other[n] = (w < EE) ? dst[re] : src[re];
        ew[n] = re;
        int tt = (int)(k >> 32);
        dtv[n] = (float)tt - (float)lu[n];
        out_lu[n] = (float)tt;
        int pos = atomicAdd(&cnt[0], 1);
        list[pos] = n;                      // winners grow from front
    } else {
        out_lu[n] = (float)lu[n];
        int pos = atomicAdd(&cnt[1], 1);
        list[NN - 1 - pos] = n;             // losers grow from back
    }
}

// ---- kernel 3: pack W into MFMA B-fragment order, bf16 ----
// frag fi = kt*NCT + ct; lane l: out col = ct*16 + (l&15) (contiguous, 300 valid),
// k = kt*32 + (l>>4)*8 + j. K rows: 0..471 w_ih^T; 472..479 0; 480..579 w_hh^T; rest 0.
__global__ void k_pack(const float* __restrict__ w_ih, const float* __restrict__ w_hh,
                       unsigned short* __restrict__ Wb) {
    int id = blockIdx.x * blockDim.x + threadIdx.x;
    if (id >= NKT * NCT * 64) return;
    int lane = id & 63;
    int ct = (id >> 6) % NCT;
    int kt = id / (64 * NCT);
    int col = ct * 16 + (lane & 15);
    int kl = lane >> 4;
    unsigned short o[8];
#pragma unroll
    for (int j = 0; j < 8; ++j) {
        int k = kt * 32 + kl * 8 + j;
        float v = 0.f;
        if (col < 300) {
            if (k < 472) v = w_ih[(size_t)col * 472 + k];
            else if (k >= 480 && k < 580) v = w_hh[(size_t)col * MEMD + (k - 480)];
        }
        o[j] = f2bf(v);
    }
    uint4 v4; __builtin_memcpy(&v4, o, 16);
    *reinterpret_cast<uint4*>(Wb + (size_t)id * 8) = v4;
}

// ---- kernel 4: WINNER nodes — full gather + K=608 MFMA dual-GEMM + GRU gates ----
// 8 waves; wave w owns col-tiles ct = w, w+8, w+16 (<19) for ALL 64 rows.
__global__ __launch_bounds__(NTHR, 4) void k_fusedW(
    const float* __restrict__ memory, const float* __restrict__ raw_msg,
    const float* __restrict__ time_w, const float* __restrict__ time_b,
    const float* __restrict__ b_ih, const float* __restrict__ b_hh,
    const int* __restrict__ other, const int* __restrict__ ew,
    const float* __restrict__ dtv, const unsigned short* __restrict__ Wb,
    const int* __restrict__ list, const int* __restrict__ cnt,
    float* __restrict__ out_mem) {
    __shared__ alignas(16) char smem[BM * RS * 2];   // 78848 B
    unsigned short* Xs = reinterpret_cast<unsigned short*>(smem);
    float* planesA = reinterpret_cast<float*>(smem);                 // [16][PLNA]
    float* planesG = reinterpret_cast<float*>(smem) + 16 * PLNA;     // [16][PLNG]
    __shared__ int s_node[BM];
    __shared__ int s_oth[BM];
    __shared__ int s_e[BM];
    __shared__ float s_dt[BM];

    const int nW = cnt[0];
    const int nbase = blockIdx.x * BM;
    if (nbase >= nW) return;
    const int tid = threadIdx.x;

    if (tid < BM) {
        int idx = nbase + tid; if (idx >= nW) idx = nW - 1;  // dup rows: benign
        int nd = list[idx];
        s_node[tid] = nd;
        s_oth[tid] = other[nd];
        s_e[tid] = ew[nd];
        s_dt[tid] = dtv[nd];
    }
    __syncthreads();

    const ushort4 z4 = {0, 0, 0, 0};
    const int w = tid >> 6;
    const int l = tid & 63;
    const int lrow = l & 15, lk = l >> 4;
    const bf16x8* Wbv = reinterpret_cast<const bf16x8*>(Wb);

    // build X tile [64][608] bf16 — no masks (all rows have winners)
    // other-mem: k [100,200)
    for (int i = tid; i < BM * 25; i += NTHR) {
        int row = i / 25, c = i - row * 25;
        float4 v = *reinterpret_cast<const float4*>(
            memory + (size_t)s_oth[row] * MEMD + 4 * c);
        *reinterpret_cast<ushort4*>(&Xs[row * RS + 100 + 4 * c]) = pack4(v);
    }
    // raw: k [200,372)
    for (int i = tid; i < BM * 43; i += NTHR) {
        int row = i / 43, c = i - row * 43;
        float4 v = *reinterpret_cast<const float4*>(
            raw_msg + (size_t)s_e[row] * RAWD + 4 * c);
        *reinterpret_cast<ushort4*>(&Xs[row * RS + 200 + 4 * c]) = pack4(v);
    }
    // self-mem: k [0,100) and [480,580) (one load, two stores)
    for (int i = tid; i < BM * 25; i += NTHR) {
        int row = i / 25, c = i - row * 25;
        float4 v = *reinterpret_cast<const float4*>(
            memory + (size_t)s_node[row] * MEMD + 4 * c);
        ushort4 h = pack4(v);
        *reinterpret_cast<ushort4*>(&Xs[row * RS + 4 * c]) = h;
        *reinterpret_cast<ushort4*>(&Xs[row * RS + 480 + 4 * c]) = h;
    }
    // enc: k [372,472)
    for (int i = tid; i < BM * 25; i += NTHR) {
        int row = i / 25, c = i - row * 25;
        float dt = s_dt[row];
        float4 wv = *reinterpret_cast<const float4*>(time_w + 4 * c);
        float4 bv = *reinterpret_cast<const float4*>(time_b + 4 * c);
        float4 v;
        v.x = fast_cos(__fadd_rn(__fmul_rn(dt, wv.x), bv.x));
        v.y = fast_cos(__fadd_rn(__fmul_rn(dt, wv.y), bv.y));
        v.z = fast_cos(__fadd_rn(__fmul_rn(dt, wv.z), bv.z));
        v.w = fast_cos(__fadd_rn(__fmul_rn(dt, wv.w), bv.w));
        *reinterpret_cast<ushort4*>(&Xs[row * RS + 372 + 4 * c]) = pack4(v);
    }
    // zero pads: k [472,480) (2 chunks) and [580,608) (7 chunks)
    for (int i = tid; i < BM * 9; i += NTHR) {
        int row = i / 9, c = i - row * 9;
        int k = (c < 2) ? (472 + 4 * c) : (580 + 4 * (c - 2));
        *reinterpret_cast<ushort4*>(&Xs[row * RS + k]) = z4;
    }
    __syncthreads();

    f32x4 acc[3][4];           // [owned ct][rowgroup]
    f32x4 acch[4];             // gh-only accumulator (each wave owns <=1 ct>=12)
#pragma unroll
    for (int i = 0; i < 3; ++i)
#pragma unroll
        for (int rg = 0; rg < 4; ++rg) acc[i][rg] = (f32x4){0.f, 0.f, 0.f, 0.f};
#pragma unroll
    for (int rg = 0; rg < 4; ++rg) acch[rg] = (f32x4){0.f, 0.f, 0.f, 0.f};

    const int r19 = blockIdx.x % NKT;

    bf16x8 b[3];
    {
        int kt0 = r19;
#pragma unroll
        for (int i = 0; i < 3; ++i) {
            int ct = w + 8 * i;
            if (ct < NCT) b[i] = Wbv[(kt0 * NCT + ct) * 64 + l];
        }
    }

    for (int idx = 0; idx < NKT; ++idx) {
        int kt = r19 + idx; if (kt >= NKT) kt -= NKT;
        bf16x8 bn[3];
#pragma unroll
        for (int i = 0; i < 3; ++i) bn[i] = b[i];
        if (idx + 1 < NKT) {
            int ktn = r19 + idx + 1; if (ktn >= NKT) ktn -= NKT;
#pragma unroll
            for (int i = 0; i < 3; ++i) {
                int ct = w + 8 * i;
                if (ct < NCT) bn[i] = Wbv[(ktn * NCT + ct) * 64 + l];
            }
        }
        bf16x8 a[4];
#pragma unroll
        for (int rg = 0; rg < 4; ++rg)
            a[rg] = *reinterpret_cast<const bf16x8*>(
                &Xs[(16 * rg + lrow) * RS + kt * 32 + lk * 8]);
        const bool tail = (kt >= 15);
#pragma unroll
        for (int i = 0; i < 3; ++i) {
            int ct = w + 8 * i;
            if (ct < NCT) {
#pragma unroll
                for (int rg = 0; rg < 4; ++rg)
                    acc[i][rg] = __builtin_amdgcn_mfma_f32_16x16x32_bf16(a[rg], b[i], acc[i][rg], 0, 0, 0);
                if (ct >= 12 && tail) {
#pragma unroll
                    for (int rg = 0; rg < 4; ++rg)
                        acch[rg] = __builtin_amdgcn_mfma_f32_16x16x32_bf16(a[rg], b[i], acch[rg], 0, 0, 0);
                }
            }
        }
#pragma unroll
        for (int i = 0; i < 3; ++i) b[i] = bn[i];
    }
    __syncthreads();   // Xs dead; smem becomes planes

    // epilogue in 4 quarters of 16 rows
    for (int qt = 0; qt < 4; ++qt) {
#pragma unroll
        for (int i = 0; i < 3; ++i) {
            int ct = w + 8 * i;
            if (ct < NCT) {
                int col = ct * 16 + lrow;
                int rl = lk * 4;
#pragma unroll
                for (int reg = 0; reg < 4; ++reg)
                    planesA[(rl + reg) * PLNA + col] = acc[i][qt][reg];
                if (ct >= 12 && col >= 200 && col < 300) {
#pragma unroll
                    for (int reg = 0; reg < 4; ++reg)
                        planesG[(rl + reg) * PLNG + (col - 200)] = acch[qt][reg];
                }
            }
        }
        __syncthreads();
        for (int idx = tid; idx < 16 * MEMD; idx += NTHR) {
            int r = idx / MEMD, m = idx - r * MEMD;
            size_t node = (size_t)s_node[qt * 16 + r];
            float p0 = planesA[r * PLNA + m];
            float p1 = planesA[r * PLNA + 100 + m];
            float p2 = planesA[r * PLNA + 200 + m];
            float p3 = planesG[r * PLNG + m];
            float rgv = p0 + b_ih[m] + b_hh[m];
            float zgv = p1 + b_ih[100 + m] + b_hh[100 + m];
            float ghn = p3 + b_hh[200 + m];
            float gin = (p2 - p3) + b_ih[200 + m];
            float rr = fsigmoid(rgv);
            float zz = fsigmoid(zgv);
            float nv = ftanh(gin + rr * ghn);
            out_mem[node * MEMD + m] = (1.f - zz) * nv + zz * memory[node * MEMD + m];
        }
        __syncthreads();
    }
}

// ---- kernel 5: LOSER nodes — gh-only (K=128 over w_hh k-tiles 15..18) + gates ----
__global__ __launch_bounds__(NTHR, 4) void k_fusedL(
    const float* __restrict__ memory,
    const float* __restrict__ b_ih, const float* __restrict__ b_hh,
    const unsigned short* __restrict__ Wb,
    const int* __restrict__ list, const int* __restrict__ cnt,
    float* __restrict__ out_mem) {
    __shared__ alignas(16) char smem[16 * PLNA * 4];   // 19712 B (>= 64*RSL*2)
    unsigned short* Xs = reinterpret_cast<unsigned short*>(smem);
    float* planesA = reinterpret_cast<float*>(smem);
    __shared__ int s_node[BM];

    const int nL = cnt[1];
    const int nbase = blockIdx.x * BM;
    if (nbase >= nL) return;
    const int tid = threadIdx.x;

    if (tid < BM) {
        int idx = nbase + tid; if (idx >= nL) idx = nL - 1;  // dup rows: benign
        s_node[tid] = list[NN - 1 - idx];
    }
    __syncthreads();

    const ushort4 z4 = {0, 0, 0, 0};
    const int w = tid >> 6;
    const int l = tid & 63;
    const int lrow = l & 15, lk = l >> 4;
    const bf16x8* Wbv = reinterpret_cast<const bf16x8*>(Wb);

    // build X [64][100] bf16 (pad to 128), stride RSL
    for (int i = tid; i < BM * 25; i += NTHR) {
        int row = i / 25, c = i - row * 25;
        float4 v = *reinterpret_cast<const float4*>(
            memory + (size_t)s_node[row] * MEMD + 4 * c);
        *reinterpret_cast<ushort4*>(&Xs[row * RSL + 4 * c]) = pack4(v);
    }
    for (int i = tid; i < BM * 7; i += NTHR) {
        int row = i / 7, c = i - row * 7;
        *reinterpret_cast<ushort4*>(&Xs[row * RSL + 100 + 4 * c]) = z4;
    }
    __syncthreads();

    f32x4 acc[3][4];
#pragma unroll
    for (int i = 0; i < 3; ++i)
#pragma unroll
        for (int rg = 0; rg < 4; ++rg) acc[i][rg] = (f32x4){0.f, 0.f, 0.f, 0.f};

    const int r4 = blockIdx.x & 3;
    for (int idx = 0; idx < 4; ++idx) {
        int ktl = (r4 + idx) & 3;
        int ktg = 15 + ktl;
        bf16x8 a[4];
#pragma unroll
        for (int rg = 0; rg < 4; ++rg)
            a[rg] = *reinterpret_cast<const bf16x8*>(
                &Xs[(16 * rg + lrow) * RSL + ktl * 32 + lk * 8]);
#pragma unroll
        for (int i = 0; i < 3; ++i) {
            int ct = w + 8 * i;
            if (ct < NCT) {
                bf16x8 b = Wbv[(ktg * NCT + ct) * 64 + l];
#pragma unroll
                for (int rg = 0; rg < 4; ++rg)
                    acc[i][rg] = __builtin_amdgcn_mfma_f32_16x16x32_bf16(a[rg], b, acc[i][rg], 0, 0, 0);
            }
        }
    }
    __syncthreads();

    // epilogue: gi = b_ih only; gh = acc + b_hh
    for (int qt = 0; qt < 4; ++qt) {
#pragma unroll
        for (int i = 0; i < 3; ++i) {
            int ct = w + 8 * i;
            if (ct < NCT) {
                int col = ct * 16 + lrow;
                int rl = lk * 4;
#pragma unroll
                for (int reg = 0; reg < 4; ++reg)
                    planesA[(rl + reg) * PLNA + col] = acc[i][qt][reg];
            }
        }
        __syncthreads();
        for (int idx = tid; idx < 16 * MEMD; idx += NTHR) {
            int r = idx / MEMD, m = idx - r * MEMD;
            size_t node = (size_t)s_node[qt * 16 + r];
            float rgv = planesA[r * PLNA + m] + b_ih[m] + b_hh[m];
            float zgv = planesA[r * PLNA + 100 + m] + b_ih[100 + m] + b_hh[100 + m];
            float ghn = planesA[r * PLNA + 200 + m] + b_hh[200 + m];
            float gin = b_ih[200 + m];
            float rr = fsigmoid(rgv);
            float zz = fsigmoid(zgv);
            float nv = ftanh(gin + rr * ghn);
            out_mem[node * MEMD + m] = (1.f - zz) * nv + zz * memory[node * MEMD + m];
        }
        __syncthreads();
    }
}

extern "C" void kernel_launch(void* const* d_in, const int* in_sizes, int n_in,
                              void* d_out, int out_size, void* d_ws, size_t ws_size,
                              hipStream_t stream) {
    const float* memory = (const float*)d_in[0];
    const float* raw_msg = (const float*)d_in[1];
    const float* time_w = (const float*)d_in[2];
    const float* time_b = (const float*)d_in[3];
    const float* w_ih = (const float*)d_in[4];
    const float* w_hh = (const float*)d_in[5];
    const float* b_ih = (const float*)d_in[6];
    const float* b_hh = (const float*)d_in[7];
    const int* last_update = (const int*)d_in[8];
    const int* src = (const int*)d_in[9];
    const int* dst = (const int*)d_in[10];
    const int* t = (const int*)d_in[11];

    char* ws = (char*)d_ws;
    unsigned long long* keys = (unsigned long long*)ws;       // 1,600,000 B @ 0
    int* other = (int*)(ws + 1600000);                        //   800,000 B
    int* ew = (int*)(ws + 2400000);                           //   800,000 B
    float* dtv = (float*)(ws + 3200000);                      //   800,000 B
    unsigned short* Wb = (unsigned short*)(ws + 4000000);     //   369,664 B
    int* list = (int*)(ws + 4370432);                         //   800,000 B
    int* cnt = (int*)(ws + 5170432);                          //        16 B

    float* out_mem = (float*)d_out;
    float* out_lu = (float*)d_out + (size_t)NN * MEMD;

    hipMemsetAsync(keys, 0, (size_t)NN * 8, stream);
    hipMemsetAsync(cnt, 0, 16, stream);
    k_winner<<<(2 * EE + 255) / 256, 256, 0, stream>>>(src, dst, t, keys);
    k_nodeinfo<<<(NN + 255) / 256, 256, 0, stream>>>(keys, src, dst, last_update,
                                                     other, ew, dtv, out_lu, list, cnt);
    k_pack<<<(NKT * NCT * 64 + 255) / 256, 256, 0, stream>>>(w_ih, w_hh, Wb);
    k_fusedW<<<NBLK, NTHR, 0, stream>>>(memory, raw_msg, time_w, time_b, b_ih, b_hh,
                                        other, ew, dtv, Wb, list, cnt, out_mem);
    k_fusedL<<<NBLK, NTHR, 0, stream>>>(memory, b_ih, b_hh, Wb, list, cnt, out_mem);
}

// Round 10
// 160.511 us; speedup vs baseline: 1.4989x; 1.4989x over previous
//
#include <hip/hip_runtime.h>
#include <hip/hip_bf16.h>
#include <math.h>

#define NN 200000
#define EE 100000
#define RAWD 172
#define MEMD 100
#define NKT 19            // k-tiles of 32 (K=608: 472 ih + 8 pad + 100 hh + 28 pad)
#define NCT 19            // col-tiles of 16, contiguous cols 0..303 (300 valid)
#define BM 64             // nodes per block
#define NTHR 512          // 8 waves
#define RS 616            // winner X row stride (shorts), 16B-aligned rows
#define RSL 136           // loser X row stride (shorts)
#define PLNA 308          // main plane row stride (floats)
#define PLNG 104          // gh plane row stride (floats)
#define NB2 782           // ceil(NN/256) and ceil(2E/256)
#define NBLKF 6250        // fused grid: worst-case W blocks + worst-case L blocks

typedef __attribute__((ext_vector_type(8))) short bf16x8;
typedef __attribute__((ext_vector_type(4))) float f32x4;

__device__ inline unsigned short f2bf(float v) {
    __hip_bfloat16 h = __float2bfloat16(v);
    unsigned short u; __builtin_memcpy(&u, &h, 2); return u;
}

__device__ inline ushort4 pack4(float4 v) {
    ushort4 r;
    r.x = f2bf(v.x); r.y = f2bf(v.y); r.z = f2bf(v.z); r.w = f2bf(v.w);
    return r;
}

__device__ inline float fsigmoid(float x) { return 1.f / (1.f + __expf(-x)); }
__device__ inline float ftanh(float x) { return 1.f - 2.f / (__expf(2.f * x) + 1.f); }

// Branchless cos: f64 range reduction, f32 polys, quadrant select via bit tricks.
__device__ inline float fast_cos(float x) {
    double xd = (double)x;
    double kd = rint(xd * 0.6366197723675814);      // x * 2/pi
    double r_d = fma(kd, -1.5707963267948966, xd);  // x - k*pi/2
    float r = (float)r_d;
    int ki = (int)kd;
    float s = r * r;
    float c = fmaf(s, fmaf(s, fmaf(s, fmaf(s, 2.4801587e-5f, -1.3888889e-3f),
                                   4.1666668e-2f), -0.5f), 1.0f);
    float sn = r * fmaf(s, fmaf(s, fmaf(s, -1.9841270e-4f, 8.3333338e-3f),
                                -1.6666667e-1f), 1.0f);
    float base = (ki & 1) ? sn : c;
    return ((ki + 1) & 2) ? -base : base;
}

// ---- kernel 1: per-node winner via packed atomicMax key = (t<<32)|(eid+1) ----
__global__ void k_winner(const int* __restrict__ src, const int* __restrict__ dst,
                         const int* __restrict__ t, unsigned long long* __restrict__ keys) {
    int e = blockIdx.x * blockDim.x + threadIdx.x;
    if (e >= 2 * EE) return;
    int re = (e < EE) ? e : e - EE;
    int node = (e < EE) ? src[re] : dst[re];
    unsigned long long key =
        ((unsigned long long)(unsigned)t[re] << 32) | (unsigned)(e + 1);
    atomicMax(&keys[node], key);
}

// ---- kernel 2a: per-256-block winner counts (ordered compaction, pass 1) ----
__global__ void k_count(const unsigned long long* __restrict__ keys,
                        int* __restrict__ blkW) {
    int n = blockIdx.x * 256 + threadIdx.x;
    bool f = (n < NN) && (keys[n] != 0ull);
    unsigned long long m = __ballot(f);
    __shared__ int s[4];
    int wave = threadIdx.x >> 6;
    if ((threadIdx.x & 63) == 0) s[wave] = __popcll(m);
    __syncthreads();
    if (threadIdx.x == 0) blkW[blockIdx.x] = s[0] + s[1] + s[2] + s[3];
}

// ---- kernel 2b: single-block exclusive scan of block counts ----
__global__ void k_scan(const int* __restrict__ blkW, int* __restrict__ offW,
                       int* __restrict__ cnt) {
    __shared__ int s[1024];
    int tid = threadIdx.x;
    int v = (tid < NB2) ? blkW[tid] : 0;
    s[tid] = v;
    __syncthreads();
    for (int off = 1; off < 1024; off <<= 1) {
        int t = (tid >= off) ? s[tid - off] : 0;
        __syncthreads();
        s[tid] += t;
        __syncthreads();
    }
    if (tid < NB2) offW[tid] = s[tid] - v;   // exclusive prefix
    if (tid == 0) { cnt[0] = s[1023]; cnt[1] = NN - s[1023]; }
}

// ---- kernel 2c: ordered scatter + winner decode + new_last_update ----
__global__ void k_scatter(const unsigned long long* __restrict__ keys,
                          const int* __restrict__ src, const int* __restrict__ dst,
                          const int* __restrict__ lu, const int* __restrict__ offW,
                          int* __restrict__ other, int* __restrict__ ew,
                          float* __restrict__ dtv, float* __restrict__ out_lu,
                          int* __restrict__ list) {
    int bid = blockIdx.x, tid = threadIdx.x;
    int n = bid * 256 + tid;
    bool valid = n < NN;
    unsigned long long k = valid ? keys[n] : 0ull;
    bool fW = valid && (k != 0ull);
    bool fL = valid && (k == 0ull);
    unsigned long long mW = __ballot(fW), mL = __ballot(fL);
    int lane = tid & 63, wave = tid >> 6;
    __shared__ int sW[4], sL[4];
    if (lane == 0) { sW[wave] = __popcll(mW); sL[wave] = __popcll(mL); }
    __syncthreads();
    int baseW = 0, baseL = 0;
    for (int i = 0; i < wave; ++i) { baseW += sW[i]; baseL += sL[i]; }
    unsigned long long below = (1ull << lane) - 1ull;
    if (fW) {
        int pos = offW[bid] + baseW + __popcll(mW & below);
        list[pos] = n;
        int w = (int)(k & 0xffffffffull) - 1;
        int re = (w < EE) ? w : w - EE;
        other[n] = (w < EE) ? dst[re] : src[re];
        ew[n] = re;
        int tt = (int)(k >> 32);
        dtv[n] = (float)tt - (float)lu[n];
        out_lu[n] = (float)tt;
    } else if (valid) {
        int pos = (bid * 256 - offW[bid]) + baseL + __popcll(mL & below);
        list[NN - 1 - pos] = n;
        out_lu[n] = (float)lu[n];
    }
}

// ---- kernel 3: pack W into MFMA B-fragment order, bf16 ----
__global__ void k_pack(const float* __restrict__ w_ih, const float* __restrict__ w_hh,
                       unsigned short* __restrict__ Wb) {
    int id = blockIdx.x * blockDim.x + threadIdx.x;
    if (id >= NKT * NCT * 64) return;
    int lane = id & 63;
    int ct = (id >> 6) % NCT;
    int kt = id / (64 * NCT);
    int col = ct * 16 + (lane & 15);
    int kl = lane >> 4;
    unsigned short o[8];
#pragma unroll
    for (int j = 0; j < 8; ++j) {
        int k = kt * 32 + kl * 8 + j;
        float v = 0.f;
        if (col < 300) {
            if (k < 472) v = w_ih[(size_t)col * 472 + k];
            else if (k >= 480 && k < 580) v = w_hh[(size_t)col * MEMD + (k - 480)];
        }
        o[j] = f2bf(v);
    }
    uint4 v4; __builtin_memcpy(&v4, o, 16);
    *reinterpret_cast<uint4*>(Wb + (size_t)id * 8) = v4;
}

// ---- kernel 4: merged winner/loser fused kernel ----
// Blocks [0, ceil(nW/64)) run the full K=608 winner pipeline on sorted winner
// nodes; remaining blocks run the K=128 gh-only loser pipeline. One launch ->
// loser blocks backfill CUs concurrently with winner blocks.
__global__ __launch_bounds__(NTHR, 4) void k_fusedWL(
    const float* __restrict__ memory, const float* __restrict__ raw_msg,
    const float* __restrict__ time_w, const float* __restrict__ time_b,
    const float* __restrict__ b_ih, const float* __restrict__ b_hh,
    const int* __restrict__ other, const int* __restrict__ ew,
    const float* __restrict__ dtv, const unsigned short* __restrict__ Wb,
    const int* __restrict__ list, const int* __restrict__ cnt,
    float* __restrict__ out_mem) {
    __shared__ alignas(16) char smem[BM * RS * 2];   // 78848 B
    unsigned short* Xs = reinterpret_cast<unsigned short*>(smem);
    float* planesA = reinterpret_cast<float*>(smem);                 // [16][PLNA]
    float* planesG = reinterpret_cast<float*>(smem) + 16 * PLNA;     // [16][PLNG]
    __shared__ int s_node[BM];
    __shared__ int s_oth[BM];
    __shared__ int s_e[BM];
    __shared__ float s_dt[BM];

    const int tid = threadIdx.x;
    const int nW = cnt[0];
    const int wblk = (nW + BM - 1) / BM;
    const int w = tid >> 6;
    const int l = tid & 63;
    const int lrow = l & 15, lk = l >> 4;
    const bf16x8* Wbv = reinterpret_cast<const bf16x8*>(Wb);
    const ushort4 z4 = {0, 0, 0, 0};

    if ((int)blockIdx.x < wblk) {
        // ================= winner path =================
        const int nbase = blockIdx.x * BM;
        if (tid < BM) {
            int idx = nbase + tid; if (idx >= nW) idx = nW - 1;  // dup tail: benign
            int nd = list[idx];
            s_node[tid] = nd;
            s_oth[tid] = other[nd];
            s_e[tid] = ew[nd];
            s_dt[tid] = dtv[nd];
        }
        __syncthreads();

        // build X tile [64][608] bf16 — no masks
        for (int i = tid; i < BM * 25; i += NTHR) {
            int row = i / 25, c = i - row * 25;
            float4 v = *reinterpret_cast<const float4*>(
                memory + (size_t)s_oth[row] * MEMD + 4 * c);
            *reinterpret_cast<ushort4*>(&Xs[row * RS + 100 + 4 * c]) = pack4(v);
        }
        for (int i = tid; i < BM * 43; i += NTHR) {
            int row = i / 43, c = i - row * 43;
            float4 v = *reinterpret_cast<const float4*>(
                raw_msg + (size_t)s_e[row] * RAWD + 4 * c);
            *reinterpret_cast<ushort4*>(&Xs[row * RS + 200 + 4 * c]) = pack4(v);
        }
        for (int i = tid; i < BM * 25; i += NTHR) {
            int row = i / 25, c = i - row * 25;
            float4 v = *reinterpret_cast<const float4*>(
                memory + (size_t)s_node[row] * MEMD + 4 * c);
            ushort4 h = pack4(v);
            *reinterpret_cast<ushort4*>(&Xs[row * RS + 4 * c]) = h;
            *reinterpret_cast<ushort4*>(&Xs[row * RS + 480 + 4 * c]) = h;
        }
        for (int i = tid; i < BM * 25; i += NTHR) {
            int row = i / 25, c = i - row * 25;
            float dt = s_dt[row];
            float4 wv = *reinterpret_cast<const float4*>(time_w + 4 * c);
            float4 bv = *reinterpret_cast<const float4*>(time_b + 4 * c);
            float4 v;
            v.x = fast_cos(__fadd_rn(__fmul_rn(dt, wv.x), bv.x));
            v.y = fast_cos(__fadd_rn(__fmul_rn(dt, wv.y), bv.y));
            v.z = fast_cos(__fadd_rn(__fmul_rn(dt, wv.z), bv.z));
            v.w = fast_cos(__fadd_rn(__fmul_rn(dt, wv.w), bv.w));
            *reinterpret_cast<ushort4*>(&Xs[row * RS + 372 + 4 * c]) = pack4(v);
        }
        for (int i = tid; i < BM * 9; i += NTHR) {
            int row = i / 9, c = i - row * 9;
            int k = (c < 2) ? (472 + 4 * c) : (580 + 4 * (c - 2));
            *reinterpret_cast<ushort4*>(&Xs[row * RS + k]) = z4;
        }
        __syncthreads();

        f32x4 acc[3][4];
        f32x4 acch[4];
#pragma unroll
        for (int i = 0; i < 3; ++i)
#pragma unroll
            for (int rg = 0; rg < 4; ++rg) acc[i][rg] = (f32x4){0.f, 0.f, 0.f, 0.f};
#pragma unroll
        for (int rg = 0; rg < 4; ++rg) acch[rg] = (f32x4){0.f, 0.f, 0.f, 0.f};

        const int r19 = blockIdx.x % NKT;
        auto ktof = [&](int idx) { int k = r19 + idx; return k >= NKT ? k - NKT : k; };
        auto loadB = [&](bf16x8 (&bb)[3], int kt) {
#pragma unroll
            for (int i = 0; i < 3; ++i) {
                int ct = w + 8 * i;
                if (ct < NCT) bb[i] = Wbv[(kt * NCT + ct) * 64 + l];
            }
        };
        auto step = [&](bf16x8 (&bb)[3], int kt) {
            bf16x8 a[4];
#pragma unroll
            for (int rg = 0; rg < 4; ++rg)
                a[rg] = *reinterpret_cast<const bf16x8*>(
                    &Xs[(16 * rg + lrow) * RS + kt * 32 + lk * 8]);
            const bool tail = (kt >= 15);
#pragma unroll
            for (int i = 0; i < 3; ++i) {
                int ct = w + 8 * i;
                if (ct < NCT) {
#pragma unroll
                    for (int rg = 0; rg < 4; ++rg)
                        acc[i][rg] = __builtin_amdgcn_mfma_f32_16x16x32_bf16(a[rg], bb[i], acc[i][rg], 0, 0, 0);
                    if (ct >= 12 && tail) {
#pragma unroll
                        for (int rg = 0; rg < 4; ++rg)
                            acch[rg] = __builtin_amdgcn_mfma_f32_16x16x32_bf16(a[rg], bb[i], acch[rg], 0, 0, 0);
                    }
                }
            }
        };

        // two-deep static double-buffered B prefetch (no register copies)
        bf16x8 b0[3], b1[3];
        loadB(b0, ktof(0));
        for (int idx = 0; idx + 1 < NKT; idx += 2) {
            loadB(b1, ktof(idx + 1));
            step(b0, ktof(idx));
            if (idx + 2 < NKT) loadB(b0, ktof(idx + 2));
            step(b1, ktof(idx + 1));
        }
        step(b0, ktof(NKT - 1));
        __syncthreads();   // Xs dead; smem becomes planes

        // epilogue in 4 quarters of 16 rows
#pragma unroll
        for (int qt = 0; qt < 4; ++qt) {
#pragma unroll
            for (int i = 0; i < 3; ++i) {
                int ct = w + 8 * i;
                if (ct < NCT) {
                    int col = ct * 16 + lrow;
                    int rl = lk * 4;
#pragma unroll
                    for (int reg = 0; reg < 4; ++reg)
                        planesA[(rl + reg) * PLNA + col] = acc[i][qt][reg];
                    if (ct >= 12 && col >= 200 && col < 300) {
#pragma unroll
                        for (int reg = 0; reg < 4; ++reg)
                            planesG[(rl + reg) * PLNG + (col - 200)] = acch[qt][reg];
                    }
                }
            }
            __syncthreads();
            for (int idx = tid; idx < 16 * MEMD; idx += NTHR) {
                int r = idx / MEMD, m = idx - r * MEMD;
                size_t node = (size_t)s_node[qt * 16 + r];
                float p0 = planesA[r * PLNA + m];
                float p1 = planesA[r * PLNA + 100 + m];
                float p2 = planesA[r * PLNA + 200 + m];
                float p3 = planesG[r * PLNG + m];
                float rgv = p0 + b_ih[m] + b_hh[m];
                float zgv = p1 + b_ih[100 + m] + b_hh[100 + m];
                float ghn = p3 + b_hh[200 + m];
                float gin = (p2 - p3) + b_ih[200 + m];
                float rr = fsigmoid(rgv);
                float zz = fsigmoid(zgv);
                float nv = ftanh(gin + rr * ghn);
                out_mem[node * MEMD + m] = (1.f - zz) * nv + zz * memory[node * MEMD + m];
            }
            __syncthreads();
        }
    } else {
        // ================= loser path =================
        const int nL = NN - nW;
        const int lbase = ((int)blockIdx.x - wblk) * BM;
        if (lbase >= nL) return;

        if (tid < BM) {
            int idx = lbase + tid; if (idx >= nL) idx = nL - 1;  // dup tail: benign
            s_node[tid] = list[NN - 1 - idx];
        }
        __syncthreads();

        // build X [64][100] bf16 (pad to 128), stride RSL
        for (int i = tid; i < BM * 25; i += NTHR) {
            int row = i / 25, c = i - row * 25;
            float4 v = *reinterpret_cast<const float4*>(
                memory + (size_t)s_node[row] * MEMD + 4 * c);
            *reinterpret_cast<ushort4*>(&Xs[row * RSL + 4 * c]) = pack4(v);
        }
        for (int i = tid; i < BM * 7; i += NTHR) {
            int row = i / 7, c = i - row * 7;
            *reinterpret_cast<ushort4*>(&Xs[row * RSL + 100 + 4 * c]) = z4;
        }
        __syncthreads();

        f32x4 acc[3][4];
#pragma unroll
        for (int i = 0; i < 3; ++i)
#pragma unroll
            for (int rg = 0; rg < 4; ++rg) acc[i][rg] = (f32x4){0.f, 0.f, 0.f, 0.f};

        const int r4 = blockIdx.x & 3;
#pragma unroll
        for (int idx = 0; idx < 4; ++idx) {
            int ktl = (r4 + idx) & 3;
            int ktg = 15 + ktl;
            bf16x8 a[4];
#pragma unroll
            for (int rg = 0; rg < 4; ++rg)
                a[rg] = *reinterpret_cast<const bf16x8*>(
                    &Xs[(16 * rg + lrow) * RSL + ktl * 32 + lk * 8]);
#pragma unroll
            for (int i = 0; i < 3; ++i) {
                int ct = w + 8 * i;
                if (ct < NCT) {
                    bf16x8 b = Wbv[(ktg * NCT + ct) * 64 + l];
#pragma unroll
                    for (int rg = 0; rg < 4; ++rg)
                        acc[i][rg] = __builtin_amdgcn_mfma_f32_16x16x32_bf16(a[rg], b, acc[i][rg], 0, 0, 0);
                }
            }
        }
        __syncthreads();

        // epilogue: gi = b_ih only; gh = acc + b_hh
#pragma unroll
        for (int qt = 0; qt < 4; ++qt) {
#pragma unroll
            for (int i = 0; i < 3; ++i) {
                int ct = w + 8 * i;
                if (ct < NCT) {
                    int col = ct * 16 + lrow;
                    int rl = lk * 4;
#pragma unroll
                    for (int reg = 0; reg < 4; ++reg)
                        planesA[(rl + reg) * PLNA + col] = acc[i][qt][reg];
                }
            }
            __syncthreads();
            for (int idx = tid; idx < 16 * MEMD; idx += NTHR) {
                int r = idx / MEMD, m = idx - r * MEMD;
                size_t node = (size_t)s_node[qt * 16 + r];
                float rgv = planesA[r * PLNA + m] + b_ih[m] + b_hh[m];
                float zgv = planesA[r * PLNA + 100 + m] + b_ih[100 + m] + b_hh[100 + m];
                float ghn = planesA[r * PLNA + 200 + m] + b_hh[200 + m];
                float gin = b_ih[200 + m];
                float rr = fsigmoid(rgv);
                float zz = fsigmoid(zgv);
                float nv = ftanh(gin + rr * ghn);
                out_mem[node * MEMD + m] = (1.f - zz) * nv + zz * memory[node * MEMD + m];
            }
            __syncthreads();
        }
    }
}

extern "C" void kernel_launch(void* const* d_in, const int* in_sizes, int n_in,
                              void* d_out, int out_size, void* d_ws, size_t ws_size,
                              hipStream_t stream) {
    const float* memory = (const float*)d_in[0];
    const float* raw_msg = (const float*)d_in[1];
    const float* time_w = (const float*)d_in[2];
    const float* time_b = (const float*)d_in[3];
    const float* w_ih = (const float*)d_in[4];
    const float* w_hh = (const float*)d_in[5];
    const float* b_ih = (const float*)d_in[6];
    const float* b_hh = (const float*)d_in[7];
    const int* last_update = (const int*)d_in[8];
    const int* src = (const int*)d_in[9];
    const int* dst = (const int*)d_in[10];
    const int* t = (const int*)d_in[11];

    char* ws = (char*)d_ws;
    unsigned long long* keys = (unsigned long long*)ws;       // 1,600,000 B @ 0
    int* other = (int*)(ws + 1600000);                        //   800,000 B
    int* ew = (int*)(ws + 2400000);                           //   800,000 B
    float* dtv = (float*)(ws + 3200000);                      //   800,000 B
    unsigned short* Wb = (unsigned short*)(ws + 4000000);     //   369,664 B
    int* list = (int*)(ws + 4370432);                         //   800,000 B
    int* cnt = (int*)(ws + 5170432);                          //        16 B
    int* blkW = (int*)(ws + 5170448);                         //     3,128 B
    int* offW = (int*)(ws + 5173576);                         //     3,128 B

    float* out_mem = (float*)d_out;
    float* out_lu = (float*)d_out + (size_t)NN * MEMD;

    hipMemsetAsync(keys, 0, (size_t)NN * 8, stream);
    k_winner<<<NB2, 256, 0, stream>>>(src, dst, t, keys);
    k_count<<<NB2, 256, 0, stream>>>(keys, blkW);
    k_scan<<<1, 1024, 0, stream>>>(blkW, offW, cnt);
    k_scatter<<<NB2, 256, 0, stream>>>(keys, src, dst, last_update, offW,
                                       other, ew, dtv, out_lu, list);
    k_pack<<<(NKT * NCT * 64 + 255) / 256, 256, 0, stream>>>(w_ih, w_hh, Wb);
    k_fusedWL<<<NBLKF, NTHR, 0, stream>>>(memory, raw_msg, time_w, time_b, b_ih, b_hh,
                                          other, ew, dtv, Wb, list, cnt, out_mem);
}

// Round 11
// 149.920 us; speedup vs baseline: 1.6048x; 1.0706x over previous
//
#include <hip/hip_runtime.h>
#include <hip/hip_bf16.h>
#include <math.h>

#define NN 200000
#define EE 100000
#define RAWD 172
#define MEMD 100
#define NKT 19            // k-tiles of 32 (K=608: 472 ih + 8 pad + 100 hh + 28 pad)
#define NCT 21            // col-tiles: ct = p*7 + jm (gate-aligned), m = jm*16+i
#define BM 64             // nodes per block
#define NTHR 512          // 8 waves
#define RS 616            // winner X row stride (shorts), 16B-aligned rows
#define RSL 136           // loser X row stride (shorts)
#define NB2 782           // ceil(NN/256)
#define NBLKF 6250        // fused grid: worst-case W blocks + worst-case L blocks

typedef __attribute__((ext_vector_type(8))) short bf16x8;
typedef __attribute__((ext_vector_type(4))) float f32x4;

__device__ inline unsigned short f2bf(float v) {
    __hip_bfloat16 h = __float2bfloat16(v);
    unsigned short u; __builtin_memcpy(&u, &h, 2); return u;
}

__device__ inline ushort4 pack4(float4 v) {
    ushort4 r;
    r.x = f2bf(v.x); r.y = f2bf(v.y); r.z = f2bf(v.z); r.w = f2bf(v.w);
    return r;
}

__device__ inline float fsigmoid(float x) { return 1.f / (1.f + __expf(-x)); }
__device__ inline float ftanh(float x) { return 1.f - 2.f / (__expf(2.f * x) + 1.f); }

// Branchless cos: f64 range reduction, f32 polys, quadrant select via bit tricks.
__device__ inline float fast_cos(float x) {
    double xd = (double)x;
    double kd = rint(xd * 0.6366197723675814);      // x * 2/pi
    double r_d = fma(kd, -1.5707963267948966, xd);  // x - k*pi/2
    float r = (float)r_d;
    int ki = (int)kd;
    float s = r * r;
    float c = fmaf(s, fmaf(s, fmaf(s, fmaf(s, 2.4801587e-5f, -1.3888889e-3f),
                                   4.1666668e-2f), -0.5f), 1.0f);
    float sn = r * fmaf(s, fmaf(s, fmaf(s, -1.9841270e-4f, 8.3333338e-3f),
                                -1.6666667e-1f), 1.0f);
    float base = (ki & 1) ? sn : c;
    return ((ki + 1) & 2) ? -base : base;
}

// ---- kernel 1: per-node winner via packed atomicMax key = (t<<32)|(eid+1) ----
__global__ void k_winner(const int* __restrict__ src, const int* __restrict__ dst,
                         const int* __restrict__ t, unsigned long long* __restrict__ keys) {
    int e = blockIdx.x * blockDim.x + threadIdx.x;
    if (e >= 2 * EE) return;
    int re = (e < EE) ? e : e - EE;
    int node = (e < EE) ? src[re] : dst[re];
    unsigned long long key =
        ((unsigned long long)(unsigned)t[re] << 32) | (unsigned)(e + 1);
    atomicMax(&keys[node], key);
}

// ---- kernel 2a: per-256-block winner counts (ordered compaction, pass 1) ----
__global__ void k_count(const unsigned long long* __restrict__ keys,
                        int* __restrict__ blkW) {
    int n = blockIdx.x * 256 + threadIdx.x;
    bool f = (n < NN) && (keys[n] != 0ull);
    unsigned long long m = __ballot(f);
    __shared__ int s[4];
    int wave = threadIdx.x >> 6;
    if ((threadIdx.x & 63) == 0) s[wave] = __popcll(m);
    __syncthreads();
    if (threadIdx.x == 0) blkW[blockIdx.x] = s[0] + s[1] + s[2] + s[3];
}

// ---- kernel 2b: single-block exclusive scan of block counts ----
__global__ void k_scan(const int* __restrict__ blkW, int* __restrict__ offW,
                       int* __restrict__ cnt) {
    __shared__ int s[1024];
    int tid = threadIdx.x;
    int v = (tid < NB2) ? blkW[tid] : 0;
    s[tid] = v;
    __syncthreads();
    for (int off = 1; off < 1024; off <<= 1) {
        int t = (tid >= off) ? s[tid - off] : 0;
        __syncthreads();
        s[tid] += t;
        __syncthreads();
    }
    if (tid < NB2) offW[tid] = s[tid] - v;   // exclusive prefix
    if (tid == 0) { cnt[0] = s[1023]; cnt[1] = NN - s[1023]; }
}

// ---- kernel 2c: ordered scatter + winner decode + new_last_update ----
__global__ void k_scatter(const unsigned long long* __restrict__ keys,
                          const int* __restrict__ src, const int* __restrict__ dst,
                          const int* __restrict__ lu, const int* __restrict__ offW,
                          int* __restrict__ other, int* __restrict__ ew,
                          float* __restrict__ dtv, float* __restrict__ out_lu,
                          int* __restrict__ list) {
    int bid = blockIdx.x, tid = threadIdx.x;
    int n = bid * 256 + tid;
    bool valid = n < NN;
    unsigned long long k = valid ? keys[n] : 0ull;
    bool fW = valid && (k != 0ull);
    bool fL = valid && (k == 0ull);
    unsigned long long mW = __ballot(fW), mL = __ballot(fL);
    int lane = tid & 63, wave = tid >> 6;
    __shared__ int sW[4], sL[4];
    if (lane == 0) { sW[wave] = __popcll(mW); sL[wave] = __popcll(mL); }
    __syncthreads();
    int baseW = 0, baseL = 0;
    for (int i = 0; i < wave; ++i) { baseW += sW[i]; baseL += sL[i]; }
    unsigned long long below = (1ull << lane) - 1ull;
    if (fW) {
        int pos = offW[bid] + baseW + __popcll(mW & below);
        list[pos] = n;
        int w = (int)(k & 0xffffffffull) - 1;
        int re = (w < EE) ? w : w - EE;
        other[n] = (w < EE) ? dst[re] : src[re];
        ew[n] = re;
        int tt = (int)(k >> 32);
        dtv[n] = (float)tt - (float)lu[n];
        out_lu[n] = (float)tt;
    } else if (valid) {
        int pos = (bid * 256 - offW[bid]) + baseL + __popcll(mL & below);
        list[NN - 1 - pos] = n;
        out_lu[n] = (float)lu[n];
    }
}

// ---- kernel 3: pack W into MFMA B-fragment order, bf16, gate-aligned cols ----
// frag fi = kt*NCT + ct; ct = p*7 + jm. lane l: m = jm*16 + (l&15) (orig col
// p*100+m, zero if m>=100), k = kt*32 + (l>>4)*8 + j.
// K rows: 0..471 w_ih^T; 472..479 0; 480..579 w_hh^T; rest 0.
__global__ void k_pack(const float* __restrict__ w_ih, const float* __restrict__ w_hh,
                       unsigned short* __restrict__ Wb) {
    int id = blockIdx.x * blockDim.x + threadIdx.x;
    if (id >= NKT * NCT * 64) return;
    int lane = id & 63;
    int ct = (id >> 6) % NCT;
    int kt = id / (64 * NCT);
    int jm = ct % 7, p = ct / 7;
    int m = jm * 16 + (lane & 15);
    int kl = lane >> 4;
    unsigned short o[8];
#pragma unroll
    for (int j = 0; j < 8; ++j) {
        int k = kt * 32 + kl * 8 + j;
        float v = 0.f;
        if (m < MEMD) {
            int c = p * MEMD + m;
            if (k < 472) v = w_ih[(size_t)c * 472 + k];
            else if (k >= 480 && k < 580) v = w_hh[(size_t)c * MEMD + (k - 480)];
        }
        o[j] = f2bf(v);
    }
    uint4 v4; __builtin_memcpy(&v4, o, 16);
    *reinterpret_cast<uint4*>(Wb + (size_t)id * 8) = v4;
}

// ---- kernel 4: merged winner/loser fused kernel, register-local epilogue ----
// Wave w<7 owns jm=w for ALL THREE gates (ct = w, 7+w, 14+w) + the gh-tail
// accumulator for jm=w -> r/z/n/gh for each output live in one thread's regs.
// No epilogue LDS exchange, no post-MFMA barriers. Wave 7 exits after build.
__global__ __launch_bounds__(NTHR, 4) void k_fusedWL(
    const float* __restrict__ memory, const float* __restrict__ raw_msg,
    const float* __restrict__ time_w, const float* __restrict__ time_b,
    const float* __restrict__ b_ih, const float* __restrict__ b_hh,
    const int* __restrict__ other, const int* __restrict__ ew,
    const float* __restrict__ dtv, const unsigned short* __restrict__ Wb,
    const int* __restrict__ list, const int* __restrict__ cnt,
    float* __restrict__ out_mem) {
    __shared__ alignas(16) unsigned short Xs[BM * RS];   // 78848 B
    __shared__ int s_node[BM];
    __shared__ int s_oth[BM];
    __shared__ int s_e[BM];
    __shared__ float s_dt[BM];

    const int tid = threadIdx.x;
    const int nW = cnt[0];
    const int wblk = (nW + BM - 1) / BM;
    const int w = tid >> 6;
    const int l = tid & 63;
    const int lrow = l & 15, lk = l >> 4;
    const bf16x8* Wbv = reinterpret_cast<const bf16x8*>(Wb);
    const ushort4 z4 = {0, 0, 0, 0};

    if ((int)blockIdx.x < wblk) {
        // ================= winner path =================
        const int nbase = blockIdx.x * BM;
        if (tid < BM) {
            int idx = nbase + tid; if (idx >= nW) idx = nW - 1;  // dup tail: benign
            int nd = list[idx];
            s_node[tid] = nd;
            s_oth[tid] = other[nd];
            s_e[tid] = ew[nd];
            s_dt[tid] = dtv[nd];
        }
        __syncthreads();

        // build X tile [64][608] bf16 — no masks
        for (int i = tid; i < BM * 25; i += NTHR) {
            int row = i / 25, c = i - row * 25;
            float4 v = *reinterpret_cast<const float4*>(
                memory + (size_t)s_oth[row] * MEMD + 4 * c);
            *reinterpret_cast<ushort4*>(&Xs[row * RS + 100 + 4 * c]) = pack4(v);
        }
        for (int i = tid; i < BM * 43; i += NTHR) {
            int row = i / 43, c = i - row * 43;
            float4 v = *reinterpret_cast<const float4*>(
                raw_msg + (size_t)s_e[row] * RAWD + 4 * c);
            *reinterpret_cast<ushort4*>(&Xs[row * RS + 200 + 4 * c]) = pack4(v);
        }
        for (int i = tid; i < BM * 25; i += NTHR) {
            int row = i / 25, c = i - row * 25;
            float4 v = *reinterpret_cast<const float4*>(
                memory + (size_t)s_node[row] * MEMD + 4 * c);
            ushort4 h = pack4(v);
            *reinterpret_cast<ushort4*>(&Xs[row * RS + 4 * c]) = h;
            *reinterpret_cast<ushort4*>(&Xs[row * RS + 480 + 4 * c]) = h;
        }
        for (int i = tid; i < BM * 25; i += NTHR) {
            int row = i / 25, c = i - row * 25;
            float dt = s_dt[row];
            float4 wv = *reinterpret_cast<const float4*>(time_w + 4 * c);
            float4 bv = *reinterpret_cast<const float4*>(time_b + 4 * c);
            float4 v;
            v.x = fast_cos(__fadd_rn(__fmul_rn(dt, wv.x), bv.x));
            v.y = fast_cos(__fadd_rn(__fmul_rn(dt, wv.y), bv.y));
            v.z = fast_cos(__fadd_rn(__fmul_rn(dt, wv.z), bv.z));
            v.w = fast_cos(__fadd_rn(__fmul_rn(dt, wv.w), bv.w));
            *reinterpret_cast<ushort4*>(&Xs[row * RS + 372 + 4 * c]) = pack4(v);
        }
        for (int i = tid; i < BM * 9; i += NTHR) {
            int row = i / 9, c = i - row * 9;
            int k = (c < 2) ? (472 + 4 * c) : (580 + 4 * (c - 2));
            *reinterpret_cast<ushort4*>(&Xs[row * RS + k]) = z4;
        }
        __syncthreads();
        if (w >= 7) return;   // wave 7: no MFMA/epilogue work; no barriers follow

        f32x4 acc[3];   // [p] for current rowgroup? no — [p][rg] flattened below
        // accumulators: [p][rowgroup], plus gh tail
        f32x4 accA[3][4];
        f32x4 acch[4];
#pragma unroll
        for (int p = 0; p < 3; ++p)
#pragma unroll
            for (int rg = 0; rg < 4; ++rg) accA[p][rg] = (f32x4){0.f, 0.f, 0.f, 0.f};
#pragma unroll
        for (int rg = 0; rg < 4; ++rg) acch[rg] = (f32x4){0.f, 0.f, 0.f, 0.f};
        (void)acc;

        const int r19 = blockIdx.x % NKT;
        auto ktof = [&](int idx) { int k = r19 + idx; return k >= NKT ? k - NKT : k; };
        auto loadB = [&](bf16x8 (&bb)[3], int kt) {
#pragma unroll
            for (int p = 0; p < 3; ++p)
                bb[p] = Wbv[(kt * NCT + p * 7 + w) * 64 + l];
        };
        auto step = [&](bf16x8 (&bb)[3], int kt) {
            bf16x8 a[4];
#pragma unroll
            for (int rg = 0; rg < 4; ++rg)
                a[rg] = *reinterpret_cast<const bf16x8*>(
                    &Xs[(16 * rg + lrow) * RS + kt * 32 + lk * 8]);
#pragma unroll
            for (int p = 0; p < 3; ++p)
#pragma unroll
                for (int rg = 0; rg < 4; ++rg)
                    accA[p][rg] = __builtin_amdgcn_mfma_f32_16x16x32_bf16(a[rg], bb[p], accA[p][rg], 0, 0, 0);
            if (kt >= 15) {
#pragma unroll
                for (int rg = 0; rg < 4; ++rg)
                    acch[rg] = __builtin_amdgcn_mfma_f32_16x16x32_bf16(a[rg], bb[2], acch[rg], 0, 0, 0);
            }
        };

        // two-deep static double-buffered B prefetch (no register copies)
        bf16x8 b0[3], b1[3];
        loadB(b0, ktof(0));
        for (int idx = 0; idx + 1 < NKT; idx += 2) {
            loadB(b1, ktof(idx + 1));
            step(b0, ktof(idx));
            if (idx + 2 < NKT) loadB(b0, ktof(idx + 2));
            step(b1, ktof(idx + 1));
        }
        step(b0, ktof(NKT - 1));

        // register-local epilogue: m = 16w + lrow, rows = 16rg + lk*4 + reg
        const int m = 16 * w + lrow;
        if (m < MEMD) {
            const float bi_r = b_ih[m],       bh_r = b_hh[m];
            const float bi_z = b_ih[100 + m], bh_z = b_hh[100 + m];
            const float bi_n = b_ih[200 + m], bh_n = b_hh[200 + m];
#pragma unroll
            for (int rg = 0; rg < 4; ++rg) {
#pragma unroll
                for (int reg = 0; reg < 4; ++reg) {
                    int row = 16 * rg + lk * 4 + reg;
                    size_t node = (size_t)s_node[row];
                    float rgv = accA[0][rg][reg] + bi_r + bh_r;
                    float zgv = accA[1][rg][reg] + bi_z + bh_z;
                    float ghn = acch[rg][reg] + bh_n;
                    float gin = (accA[2][rg][reg] - acch[rg][reg]) + bi_n;
                    float rr = fsigmoid(rgv);
                    float zz = fsigmoid(zgv);
                    float nv = ftanh(gin + rr * ghn);
                    out_mem[node * MEMD + m] =
                        (1.f - zz) * nv + zz * memory[node * MEMD + m];
                }
            }
        }
    } else {
        // ================= loser path =================
        const int nL = NN - nW;
        const int lbase = ((int)blockIdx.x - wblk) * BM;
        if (lbase >= nL) return;

        if (tid < BM) {
            int idx = lbase + tid; if (idx >= nL) idx = nL - 1;  // dup tail: benign
            s_node[tid] = list[NN - 1 - idx];
        }
        __syncthreads();

        // build X [64][100] bf16 (pad to 128), stride RSL
        for (int i = tid; i < BM * 25; i += NTHR) {
            int row = i / 25, c = i - row * 25;
            float4 v = *reinterpret_cast<const float4*>(
                memory + (size_t)s_node[row] * MEMD + 4 * c);
            *reinterpret_cast<ushort4*>(&Xs[row * RSL + 4 * c]) = pack4(v);
        }
        for (int i = tid; i < BM * 7; i += NTHR) {
            int row = i / 7, c = i - row * 7;
            *reinterpret_cast<ushort4*>(&Xs[row * RSL + 100 + 4 * c]) = z4;
        }
        __syncthreads();
        if (w >= 7) return;

        f32x4 accA[3][4];
#pragma unroll
        for (int p = 0; p < 3; ++p)
#pragma unroll
            for (int rg = 0; rg < 4; ++rg) accA[p][rg] = (f32x4){0.f, 0.f, 0.f, 0.f};

#pragma unroll
        for (int ktl = 0; ktl < 4; ++ktl) {
            int ktg = 15 + ktl;
            bf16x8 a[4];
#pragma unroll
            for (int rg = 0; rg < 4; ++rg)
                a[rg] = *reinterpret_cast<const bf16x8*>(
                    &Xs[(16 * rg + lrow) * RSL + ktl * 32 + lk * 8]);
#pragma unroll
            for (int p = 0; p < 3; ++p) {
                bf16x8 b = Wbv[(ktg * NCT + p * 7 + w) * 64 + l];
#pragma unroll
                for (int rg = 0; rg < 4; ++rg)
                    accA[p][rg] = __builtin_amdgcn_mfma_f32_16x16x32_bf16(a[rg], b, accA[p][rg], 0, 0, 0);
            }
        }

        // register-local epilogue: gi = b_ih only; gh = accA + b_hh
        const int m = 16 * w + lrow;
        if (m < MEMD) {
            const float bi_r = b_ih[m],       bh_r = b_hh[m];
            const float bi_z = b_ih[100 + m], bh_z = b_hh[100 + m];
            const float bi_n = b_ih[200 + m], bh_n = b_hh[200 + m];
#pragma unroll
            for (int rg = 0; rg < 4; ++rg) {
#pragma unroll
                for (int reg = 0; reg < 4; ++reg) {
                    int row = 16 * rg + lk * 4 + reg;
                    size_t node = (size_t)s_node[row];
                    float rgv = accA[0][rg][reg] + bi_r + bh_r;
                    float zgv = accA[1][rg][reg] + bi_z + bh_z;
                    float ghn = accA[2][rg][reg] + bh_n;
                    float gin = bi_n;
                    float rr = fsigmoid(rgv);
                    float zz = fsigmoid(zgv);
                    float nv = ftanh(gin + rr * ghn);
                    out_mem[node * MEMD + m] =
                        (1.f - zz) * nv + zz * memory[node * MEMD + m];
                }
            }
        }
    }
}

extern "C" void kernel_launch(void* const* d_in, const int* in_sizes, int n_in,
                              void* d_out, int out_size, void* d_ws, size_t ws_size,
                              hipStream_t stream) {
    const float* memory = (const float*)d_in[0];
    const float* raw_msg = (const float*)d_in[1];
    const float* time_w = (const float*)d_in[2];
    const float* time_b = (const float*)d_in[3];
    const float* w_ih = (const float*)d_in[4];
    const float* w_hh = (const float*)d_in[5];
    const float* b_ih = (const float*)d_in[6];
    const float* b_hh = (const float*)d_in[7];
    const int* last_update = (const int*)d_in[8];
    const int* src = (const int*)d_in[9];
    const int* dst = (const int*)d_in[10];
    const int* t = (const int*)d_in[11];

    char* ws = (char*)d_ws;
    unsigned long long* keys = (unsigned long long*)ws;       // 1,600,000 B @ 0
    int* other = (int*)(ws + 1600000);                        //   800,000 B
    int* ew = (int*)(ws + 2400000);                           //   800,000 B
    float* dtv = (float*)(ws + 3200000);                      //   800,000 B
    unsigned short* Wb = (unsigned short*)(ws + 4000000);     //   408,576 B
    int* list = (int*)(ws + 4408576);                         //   800,000 B
    int* cnt = (int*)(ws + 5208576);                          //        16 B
    int* blkW = (int*)(ws + 5208592);                         //     3,128 B
    int* offW = (int*)(ws + 5211720);                         //     3,128 B

    float* out_mem = (float*)d_out;
    float* out_lu = (float*)d_out + (size_t)NN * MEMD;

    hipMemsetAsync(keys, 0, (size_t)NN * 8, stream);
    k_winner<<<NB2, 256, 0, stream>>>(src, dst, t, keys);
    k_count<<<NB2, 256, 0, stream>>>(keys, blkW);
    k_scan<<<1, 1024, 0, stream>>>(blkW, offW, cnt);
    k_scatter<<<NB2, 256, 0, stream>>>(keys, src, dst, last_update, offW,
                                       other, ew, dtv, out_lu, list);
    k_pack<<<(NKT * NCT * 64 + 255) / 256, 256, 0, stream>>>(w_ih, w_hh, Wb);
    k_fusedWL<<<NBLKF, NTHR, 0, stream>>>(memory, raw_msg, time_w, time_b, b_ih, b_hh,
                                          other, ew, dtv, Wb, list, cnt, out_mem);
}